// Round 1
// baseline (412.042 us; speedup 1.0000x reference)
//
#include <hip/hip_runtime.h>
#include <hip/hip_bf16.h>

typedef float f32x4 __attribute__((ext_vector_type(4)));
typedef short s16x8 __attribute__((ext_vector_type(8)));
typedef short s16x4 __attribute__((ext_vector_type(4)));

#define B_ 4
#define T_ 2048
#define C_ 1024
#define H_ 16
#define DH_ 64
#define M_ (B_*T_)      // 8192
#define N3_ (3*C_)      // 3072

static __device__ __forceinline__ short f2bf(float f) {
    __hip_bfloat16 h = __float2bfloat16(f);
    return *reinterpret_cast<short*>(&h);
}

// ---------------- prep kernels ----------------

__global__ __launch_bounds__(256) void cast_f32_bf16(
    const float* __restrict__ in, short* __restrict__ out, int n8)
{
    int i = blockIdx.x * 256 + threadIdx.x;
    if (i >= n8) return;
    float4 a = *(const float4*)&in[i * 8];
    float4 b = *(const float4*)&in[i * 8 + 4];
    s16x8 o = { f2bf(a.x), f2bf(a.y), f2bf(a.z), f2bf(a.w),
                f2bf(b.x), f2bf(b.y), f2bf(b.z), f2bf(b.w) };
    *(s16x8*)&out[i * 8] = o;
}

// src [K][N] f32 row-major  ->  dst [N][K] bf16 row-major
__global__ __launch_bounds__(256) void transpose_cast(
    const float* __restrict__ src, short* __restrict__ dst, int K, int N)
{
    __shared__ short t[64][66];
    int tid = threadIdx.x;
    int n0 = blockIdx.x * 64, k0 = blockIdx.y * 64;
    #pragma unroll
    for (int p = 0; p < 4; ++p) {
        int cid = tid + p * 256;          // 0..1023
        int r = cid >> 4, c4 = cid & 15;  // r: k-row, c4: n-col group of 4
        float4 v = *(const float4*)&src[(k0 + r) * N + n0 + c4 * 4];
        t[r][c4 * 4 + 0] = f2bf(v.x);
        t[r][c4 * 4 + 1] = f2bf(v.y);
        t[r][c4 * 4 + 2] = f2bf(v.z);
        t[r][c4 * 4 + 3] = f2bf(v.w);
    }
    __syncthreads();
    #pragma unroll
    for (int p = 0; p < 4; ++p) {
        int cid = tid + p * 256;
        int r = cid >> 4, c4 = cid & 15;  // r: n-row, c4: k group of 4
        s16x4 ov;
        #pragma unroll
        for (int j = 0; j < 4; ++j) ov[j] = t[c4 * 4 + j][r];
        *(s16x4*)&dst[(n0 + r) * K + k0 + c4 * 4] = ov;
    }
}

// ---------------- GEMM: C[M][N] = A[M][1024] * Bt[N][1024]^T (+bias) ----------------
// MODE 0: write f32 to out ([M][1024])
// MODE 1: scatter bf16 q/k/v ([B,H,T,DH] each), N = 3072

template<int MODE>
__global__ __launch_bounds__(256) void gemm_bt(
    const short* __restrict__ A, const short* __restrict__ Bt,
    const float* __restrict__ bias, float* __restrict__ out,
    short* __restrict__ qout, short* __restrict__ kout, short* __restrict__ vout)
{
    const int K = 1024;
    __shared__ short As[128][72];
    __shared__ short Bs[128][72];
    int tid = threadIdx.x;
    int lane = tid & 63, w = tid >> 6;
    int d = lane & 15, g = lane >> 4;
    int wm = w >> 1, wn = w & 1;
    int m0 = blockIdx.y * 128, n0 = blockIdx.x * 128;

    f32x4 acc[4][4];
    #pragma unroll
    for (int i = 0; i < 4; ++i)
        #pragma unroll
        for (int j = 0; j < 4; ++j) acc[i][j] = (f32x4){0.f, 0.f, 0.f, 0.f};

    for (int kt = 0; kt < K; kt += 64) {
        #pragma unroll
        for (int p = 0; p < 4; ++p) {
            int cid = tid + p * 256;          // 0..1023
            int r = cid >> 3, c8 = cid & 7;   // 128 rows x 8 chunks
            *(s16x8*)&As[r][c8 * 8] = *(const s16x8*)&A[(m0 + r) * K + kt + c8 * 8];
            *(s16x8*)&Bs[r][c8 * 8] = *(const s16x8*)&Bt[(n0 + r) * K + kt + c8 * 8];
        }
        __syncthreads();
        #pragma unroll
        for (int ks = 0; ks < 2; ++ks) {
            s16x8 af[4], bf[4];
            #pragma unroll
            for (int i = 0; i < 4; ++i) {
                af[i] = *(const s16x8*)&As[wm * 64 + i * 16 + d][ks * 32 + 8 * g];
                bf[i] = *(const s16x8*)&Bs[wn * 64 + i * 16 + d][ks * 32 + 8 * g];
            }
            #pragma unroll
            for (int mi = 0; mi < 4; ++mi)
                #pragma unroll
                for (int ni = 0; ni < 4; ++ni)
                    acc[mi][ni] = __builtin_amdgcn_mfma_f32_16x16x32_bf16(
                        af[mi], bf[ni], acc[mi][ni], 0, 0, 0);
        }
        __syncthreads();
    }

    #pragma unroll
    for (int mi = 0; mi < 4; ++mi)
        #pragma unroll
        for (int ni = 0; ni < 4; ++ni)
            #pragma unroll
            for (int r = 0; r < 4; ++r) {
                int gm = m0 + wm * 64 + mi * 16 + g * 4 + r;
                int gn = n0 + wn * 64 + ni * 16 + d;
                float val = acc[mi][ni][r] + bias[gn];
                if (MODE == 0) {
                    out[gm * 1024 + gn] = val;
                } else {
                    int b = gm >> 11, t = gm & 2047;
                    int which = gn >> 10, cc = gn & 1023;
                    int h = cc >> 6, dh = cc & 63;
                    short* dst = (which == 0) ? qout : ((which == 1) ? kout : vout);
                    dst[((b * 16 + h) * 2048 + t) * 64 + dh] = f2bf(val);
                }
            }
}

// ---------------- flash attention ----------------
// q,k,v: [B,H,T,64] bf16; y: [B,T,1024] bf16

__global__ __launch_bounds__(256) void attn_fwd(
    const short* __restrict__ q, const short* __restrict__ kk,
    const short* __restrict__ v, short* __restrict__ y)
{
    __shared__ short Ks[64][72];
    __shared__ short Vt[64][72];     // [dh][key]
    __shared__ short Ps[4][16][72];
    int tid = threadIdx.x, lane = tid & 63, w = tid >> 6;
    int d = lane & 15, g = lane >> 4;
    int qt = blockIdx.x, bh = blockIdx.y;
    int b = bh >> 4, h = bh & 15;
    const int hb = bh * (2048 * 64);
    int qrow = qt * 64 + w * 16;

    s16x8 qf0 = *(const s16x8*)&q[hb + (qrow + d) * 64 + 8 * g];
    s16x8 qf1 = *(const s16x8*)&q[hb + (qrow + d) * 64 + 32 + 8 * g];

    f32x4 o[4];
    float m[4], l[4];
    #pragma unroll
    for (int r = 0; r < 4; ++r) { m[r] = -1e30f; l[r] = 0.f; o[r] = (f32x4){0.f,0.f,0.f,0.f}; }

    for (int kt = 0; kt <= qt; ++kt) {
        __syncthreads();
        #pragma unroll
        for (int p = 0; p < 2; ++p) {
            int cid = tid + p * 256;        // 0..511
            int r = cid >> 3, c8 = cid & 7; // 64 rows x 8 chunks
            *(s16x8*)&Ks[r][c8 * 8] = *(const s16x8*)&kk[hb + (kt * 64 + r) * 64 + c8 * 8];
            s16x8 vv = *(const s16x8*)&v[hb + (kt * 64 + r) * 64 + c8 * 8];
            #pragma unroll
            for (int j = 0; j < 8; ++j) Vt[c8 * 8 + j][r] = vv[j];
        }
        __syncthreads();

        f32x4 s[4];
        #pragma unroll
        for (int ni = 0; ni < 4; ++ni) s[ni] = (f32x4){0.f,0.f,0.f,0.f};
        #pragma unroll
        for (int ni = 0; ni < 4; ++ni) {
            s16x8 b0 = *(const s16x8*)&Ks[ni * 16 + d][8 * g];
            s[ni] = __builtin_amdgcn_mfma_f32_16x16x32_bf16(qf0, b0, s[ni], 0, 0, 0);
            s16x8 b1 = *(const s16x8*)&Ks[ni * 16 + d][32 + 8 * g];
            s[ni] = __builtin_amdgcn_mfma_f32_16x16x32_bf16(qf1, b1, s[ni], 0, 0, 0);
        }

        bool diag = (kt == qt);
        #pragma unroll
        for (int r = 0; r < 4; ++r) {
            int grow = qt * 64 + w * 16 + g * 4 + r;
            float mx = -1e30f;
            #pragma unroll
            for (int ni = 0; ni < 4; ++ni) {
                float sv = s[ni][r] * 0.125f;
                if (diag && (kt * 64 + ni * 16 + d > grow)) sv = -1e30f;
                s[ni][r] = sv;
                mx = fmaxf(mx, sv);
            }
            mx = fmaxf(mx, __shfl_xor(mx, 1));
            mx = fmaxf(mx, __shfl_xor(mx, 2));
            mx = fmaxf(mx, __shfl_xor(mx, 4));
            mx = fmaxf(mx, __shfl_xor(mx, 8));
            float mnew = fmaxf(m[r], mx);
            float alpha = __expf(m[r] - mnew);
            m[r] = mnew;
            float sum = 0.f;
            #pragma unroll
            for (int ni = 0; ni < 4; ++ni) {
                float pv = __expf(s[ni][r] - mnew);
                s[ni][r] = pv;
                sum += pv;
            }
            sum += __shfl_xor(sum, 1);
            sum += __shfl_xor(sum, 2);
            sum += __shfl_xor(sum, 4);
            sum += __shfl_xor(sum, 8);
            l[r] = l[r] * alpha + sum;
            #pragma unroll
            for (int df = 0; df < 4; ++df) o[df][r] *= alpha;
            #pragma unroll
            for (int ni = 0; ni < 4; ++ni) Ps[w][g * 4 + r][ni * 16 + d] = f2bf(s[ni][r]);
        }

        s16x8 pa0 = *(const s16x8*)&Ps[w][d][8 * g];
        s16x8 pa1 = *(const s16x8*)&Ps[w][d][32 + 8 * g];
        #pragma unroll
        for (int df = 0; df < 4; ++df) {
            s16x8 b0 = *(const s16x8*)&Vt[df * 16 + d][8 * g];
            o[df] = __builtin_amdgcn_mfma_f32_16x16x32_bf16(pa0, b0, o[df], 0, 0, 0);
            s16x8 b1 = *(const s16x8*)&Vt[df * 16 + d][32 + 8 * g];
            o[df] = __builtin_amdgcn_mfma_f32_16x16x32_bf16(pa1, b1, o[df], 0, 0, 0);
        }
    }

    #pragma unroll
    for (int df = 0; df < 4; ++df)
        #pragma unroll
        for (int r = 0; r < 4; ++r) {
            int grow = qt * 64 + w * 16 + g * 4 + r;
            float val = o[df][r] / l[r];
            y[(b * 2048 + grow) * 1024 + h * 64 + df * 16 + d] = f2bf(val);
        }
}

// ---------------- launch ----------------

extern "C" void kernel_launch(void* const* d_in, const int* in_sizes, int n_in,
                              void* d_out, int out_size, void* d_ws, size_t ws_size,
                              hipStream_t stream)
{
    const float* x    = (const float*)d_in[0];
    const float* Wqkv = (const float*)d_in[1];
    const float* bqkv = (const float*)d_in[2];
    const float* Wout = (const float*)d_in[3];
    const float* bout = (const float*)d_in[4];
    float* out = (float*)d_out;

    char* ws = (char*)d_ws;
    short* xbf   = (short*)ws;  ws += (size_t)M_ * C_ * 2;      // 16 MB
    short* wqkvT = (short*)ws;  ws += (size_t)N3_ * C_ * 2;     // 6 MB
    short* woutT = (short*)ws;  ws += (size_t)C_ * C_ * 2;      // 2 MB
    short* qb    = (short*)ws;  ws += (size_t)M_ * C_ * 2;      // 16 MB
    short* kb    = (short*)ws;  ws += (size_t)M_ * C_ * 2;
    short* vb    = (short*)ws;  ws += (size_t)M_ * C_ * 2;
    short* yb    = (short*)ws;  ws += (size_t)M_ * C_ * 2;

    // prep
    cast_f32_bf16<<<(M_ * C_ / 8 + 255) / 256, 256, 0, stream>>>(x, xbf, M_ * C_ / 8);
    transpose_cast<<<dim3(N3_ / 64, C_ / 64), 256, 0, stream>>>(Wqkv, wqkvT, C_, N3_);
    transpose_cast<<<dim3(C_ / 64, C_ / 64), 256, 0, stream>>>(Wout, woutT, C_, C_);

    // qkv projection
    gemm_bt<1><<<dim3(N3_ / 128, M_ / 128), 256, 0, stream>>>(
        xbf, wqkvT, bqkv, nullptr, qb, kb, vb);

    // attention
    attn_fwd<<<dim3(T_ / 64, B_ * H_), 256, 0, stream>>>(qb, kb, vb, yb);

    // output projection
    gemm_bt<0><<<dim3(C_ / 128, M_ / 128), 256, 0, stream>>>(
        yb, woutT, bout, out, nullptr, nullptr, nullptr);
}

// Round 2
// 323.255 us; speedup vs baseline: 1.2747x; 1.2747x over previous
//
#include <hip/hip_runtime.h>
#include <hip/hip_bf16.h>

typedef float f32x4 __attribute__((ext_vector_type(4)));
typedef short s16x8 __attribute__((ext_vector_type(8)));
typedef short s16x4 __attribute__((ext_vector_type(4)));

#define B_ 4
#define T_ 2048
#define C_ 1024
#define H_ 16
#define DH_ 64
#define M_ (B_*T_)      // 8192
#define N3_ (3*C_)      // 3072

static __device__ __forceinline__ short f2bf(float f) {
    __hip_bfloat16 h = __float2bfloat16(f);
    return *reinterpret_cast<short*>(&h);
}

// async global->LDS, 16B per lane. LDS dest is wave-uniform base + lane*16.
static __device__ __forceinline__ void gload16(const void* g, void* l) {
    __builtin_amdgcn_global_load_lds(
        (const __attribute__((address_space(1))) void*)g,
        (__attribute__((address_space(3))) void*)l, 16, 0, 0);
}

// swizzled b128 fragment read from a linear [rows][64-short] LDS tile.
// chunk = 16B column index (0..7); swizzle matches the staged source swizzle.
static __device__ __forceinline__ s16x8 lds_frag(const short* base, int row, int chunk) {
    return *(const s16x8*)&base[(row << 6) + ((chunk ^ (row & 7)) << 3)];
}

// ---------------- prep kernels ----------------

__global__ __launch_bounds__(256) void cast_f32_bf16(
    const float* __restrict__ in, short* __restrict__ out, int n8)
{
    int i = blockIdx.x * 256 + threadIdx.x;
    if (i >= n8) return;
    float4 a = *(const float4*)&in[i * 8];
    float4 b = *(const float4*)&in[i * 8 + 4];
    s16x8 o = { f2bf(a.x), f2bf(a.y), f2bf(a.z), f2bf(a.w),
                f2bf(b.x), f2bf(b.y), f2bf(b.z), f2bf(b.w) };
    *(s16x8*)&out[i * 8] = o;
}

// src [K][N] f32 row-major  ->  dst [N][K] bf16 row-major
__global__ __launch_bounds__(256) void transpose_cast(
    const float* __restrict__ src, short* __restrict__ dst, int K, int N)
{
    __shared__ short t[64][66];
    int tid = threadIdx.x;
    int n0 = blockIdx.x * 64, k0 = blockIdx.y * 64;
    #pragma unroll
    for (int p = 0; p < 4; ++p) {
        int cid = tid + p * 256;          // 0..1023
        int r = cid >> 4, c4 = cid & 15;  // r: k-row, c4: n-col group of 4
        float4 v = *(const float4*)&src[(size_t)(k0 + r) * N + n0 + c4 * 4];
        t[r][c4 * 4 + 0] = f2bf(v.x);
        t[r][c4 * 4 + 1] = f2bf(v.y);
        t[r][c4 * 4 + 2] = f2bf(v.z);
        t[r][c4 * 4 + 3] = f2bf(v.w);
    }
    __syncthreads();
    #pragma unroll
    for (int p = 0; p < 4; ++p) {
        int cid = tid + p * 256;
        int r = cid >> 4, c4 = cid & 15;  // r: n-row, c4: k group of 4
        s16x4 ov;
        #pragma unroll
        for (int j = 0; j < 4; ++j) ov[j] = t[c4 * 4 + j][r];
        *(s16x4*)&dst[(size_t)(n0 + r) * K + k0 + c4 * 4] = ov;
    }
}

// ---------------- GEMM: C[M][N] = A[M][1024] * Bt[N][1024]^T (+bias) ----------------
// MODE 0: write f32 to out ([M][1024])
// MODE 1: scatter bf16 q/k ([B,H,T,DH]) and v transposed ([B,H,DH,T]), N = 3072

template<int MODE>
__global__ __launch_bounds__(256) void gemm_bt(
    const short* __restrict__ A, const short* __restrict__ Bt,
    const float* __restrict__ bias, float* __restrict__ out,
    short* __restrict__ qout, short* __restrict__ kout, short* __restrict__ vout)
{
    const int K = 1024;
    __shared__ short As[128 * 64];
    __shared__ short Bs[128 * 64];
    int tid = threadIdx.x;
    int lane = tid & 63, w = tid >> 6;
    int d = lane & 15, g = lane >> 4;
    int wm = w >> 1, wn = w & 1;
    int m0 = blockIdx.y * 128, n0 = blockIdx.x * 128;

    f32x4 acc[4][4];
    #pragma unroll
    for (int i = 0; i < 4; ++i)
        #pragma unroll
        for (int j = 0; j < 4; ++j) acc[i][j] = (f32x4){0.f, 0.f, 0.f, 0.f};

    for (int kt = 0; kt < K; kt += 64) {
        #pragma unroll
        for (int p = 0; p < 4; ++p) {
            int cid = p * 256 + tid;          // 0..1023
            int r = cid >> 3, c8 = cid & 7;   // 128 rows x 8 16B-chunks
            int co = (c8 ^ (r & 7)) << 3;     // inverse-swizzled source column
            int dofs = (p * 256 + (tid & ~63)) * 8;  // wave-uniform dest (shorts)
            gload16(&A[(size_t)(m0 + r) * K + kt + co], &As[dofs]);
            gload16(&Bt[(size_t)(n0 + r) * K + kt + co], &Bs[dofs]);
        }
        __syncthreads();
        #pragma unroll
        for (int ks = 0; ks < 2; ++ks) {
            s16x8 af[4], bf[4];
            #pragma unroll
            for (int i = 0; i < 4; ++i) {
                af[i] = lds_frag(As, wm * 64 + i * 16 + d, ks * 4 + g);
                bf[i] = lds_frag(Bs, wn * 64 + i * 16 + d, ks * 4 + g);
            }
            #pragma unroll
            for (int mi = 0; mi < 4; ++mi)
                #pragma unroll
                for (int ni = 0; ni < 4; ++ni)
                    acc[mi][ni] = __builtin_amdgcn_mfma_f32_16x16x32_bf16(
                        af[mi], bf[ni], acc[mi][ni], 0, 0, 0);
        }
        __syncthreads();
    }

    #pragma unroll
    for (int mi = 0; mi < 4; ++mi)
        #pragma unroll
        for (int ni = 0; ni < 4; ++ni) {
            int gn = n0 + wn * 64 + ni * 16 + d;
            float bv = bias[gn];
            int gm0 = m0 + wm * 64 + mi * 16 + g * 4;
            if (MODE == 0) {
                #pragma unroll
                for (int r = 0; r < 4; ++r)
                    out[(size_t)(gm0 + r) * 1024 + gn] = acc[mi][ni][r] + bv;
            } else {
                int which = gn >> 10, cc = gn & 1023;
                int h = cc >> 6, dh = cc & 63;
                int b = gm0 >> 11, t0 = gm0 & 2047;
                if (which == 2) {
                    s16x4 pv;
                    #pragma unroll
                    for (int r = 0; r < 4; ++r) pv[r] = f2bf(acc[mi][ni][r] + bv);
                    *(s16x4*)&vout[((size_t)(b * 16 + h) * 64 + dh) * 2048 + t0] = pv;
                } else {
                    short* dst = which ? kout : qout;
                    #pragma unroll
                    for (int r = 0; r < 4; ++r)
                        dst[((size_t)(b * 16 + h) * 2048 + (t0 + r)) * 64 + dh] =
                            f2bf(acc[mi][ni][r] + bv);
                }
            }
        }
}

// ---------------- flash attention ----------------
// q,k: [B,H,T,64] bf16; vt: [B,H,64,T] bf16 (pre-transposed); y: [B,T,1024] bf16

__global__ __launch_bounds__(256) void attn_fwd(
    const short* __restrict__ q, const short* __restrict__ kk,
    const short* __restrict__ vt, short* __restrict__ y)
{
    __shared__ short Ks[2][64 * 64];
    __shared__ short Vs[2][64 * 64];
    __shared__ short Ps[4][16][72];
    int tid = threadIdx.x, lane = tid & 63, w = tid >> 6;
    int d = lane & 15, g = lane >> 4;
    int qt = (int)gridDim.x - 1 - (int)blockIdx.x;   // longest blocks first
    int bh = blockIdx.y;
    int b = bh >> 4, h = bh & 15;
    const size_t hb = (size_t)bh * 2048 * 64;
    int qrow = qt * 64 + w * 16;

    s16x8 qf0 = *(const s16x8*)&q[hb + (size_t)(qrow + d) * 64 + 8 * g];
    s16x8 qf1 = *(const s16x8*)&q[hb + (size_t)(qrow + d) * 64 + 32 + 8 * g];

    f32x4 o[4];
    float m[4], l[4];
    #pragma unroll
    for (int r = 0; r < 4; ++r) { m[r] = -1e30f; l[r] = 0.f; o[r] = (f32x4){0.f,0.f,0.f,0.f}; }

    auto stage = [&](int buf, int kt2) {
        #pragma unroll
        for (int p = 0; p < 2; ++p) {
            int cid = p * 256 + tid;          // 0..511
            int r = cid >> 3, c8 = cid & 7;   // 64 rows x 8 16B-chunks
            int co = (c8 ^ (r & 7)) << 3;
            int dofs = (p * 256 + (tid & ~63)) * 8;
            gload16(&kk[hb + (size_t)(kt2 * 64 + r) * 64 + co], &Ks[buf][dofs]);
            gload16(&vt[hb + (size_t)r * 2048 + kt2 * 64 + co], &Vs[buf][dofs]);
        }
    };

    stage(0, 0);
    __syncthreads();
    int cur = 0;

    for (int kt = 0; kt <= qt; ++kt) {
        if (kt < qt) stage(cur ^ 1, kt + 1);   // prefetch overlaps compute
        const short* Kb = Ks[cur];
        const short* Vb = Vs[cur];

        f32x4 s[4];
        #pragma unroll
        for (int ni = 0; ni < 4; ++ni) s[ni] = (f32x4){0.f,0.f,0.f,0.f};
        #pragma unroll
        for (int ni = 0; ni < 4; ++ni) {
            s[ni] = __builtin_amdgcn_mfma_f32_16x16x32_bf16(
                qf0, lds_frag(Kb, ni * 16 + d, g), s[ni], 0, 0, 0);
            s[ni] = __builtin_amdgcn_mfma_f32_16x16x32_bf16(
                qf1, lds_frag(Kb, ni * 16 + d, 4 + g), s[ni], 0, 0, 0);
        }

        bool diag = (kt == qt);
        #pragma unroll
        for (int r = 0; r < 4; ++r) {
            int grow = qt * 64 + w * 16 + g * 4 + r;
            float mx = -1e30f;
            #pragma unroll
            for (int ni = 0; ni < 4; ++ni) {
                float sv = s[ni][r] * 0.125f;
                if (diag && (kt * 64 + ni * 16 + d > grow)) sv = -1e30f;
                s[ni][r] = sv;
                mx = fmaxf(mx, sv);
            }
            mx = fmaxf(mx, __shfl_xor(mx, 1));
            mx = fmaxf(mx, __shfl_xor(mx, 2));
            mx = fmaxf(mx, __shfl_xor(mx, 4));
            mx = fmaxf(mx, __shfl_xor(mx, 8));
            float mnew = fmaxf(m[r], mx);
            float alpha = __expf(m[r] - mnew);
            m[r] = mnew;
            float sum = 0.f;
            #pragma unroll
            for (int ni = 0; ni < 4; ++ni) {
                float pv = __expf(s[ni][r] - mnew);
                s[ni][r] = pv;
                sum += pv;
            }
            sum += __shfl_xor(sum, 1);
            sum += __shfl_xor(sum, 2);
            sum += __shfl_xor(sum, 4);
            sum += __shfl_xor(sum, 8);
            l[r] = l[r] * alpha + sum;
            #pragma unroll
            for (int df = 0; df < 4; ++df) o[df][r] *= alpha;
            #pragma unroll
            for (int ni = 0; ni < 4; ++ni) Ps[w][g * 4 + r][ni * 16 + d] = f2bf(s[ni][r]);
        }

        s16x8 pa0 = *(const s16x8*)&Ps[w][d][8 * g];
        s16x8 pa1 = *(const s16x8*)&Ps[w][d][32 + 8 * g];
        #pragma unroll
        for (int df = 0; df < 4; ++df) {
            o[df] = __builtin_amdgcn_mfma_f32_16x16x32_bf16(
                pa0, lds_frag(Vb, df * 16 + d, g), o[df], 0, 0, 0);
            o[df] = __builtin_amdgcn_mfma_f32_16x16x32_bf16(
                pa1, lds_frag(Vb, df * 16 + d, 4 + g), o[df], 0, 0, 0);
        }

        __syncthreads();
        cur ^= 1;
    }

    #pragma unroll
    for (int df = 0; df < 4; ++df)
        #pragma unroll
        for (int r = 0; r < 4; ++r) {
            int grow = qt * 64 + w * 16 + g * 4 + r;
            float val = o[df][r] / l[r];
            y[(size_t)(b * 2048 + grow) * 1024 + h * 64 + df * 16 + d] = f2bf(val);
        }
}

// ---------------- launch ----------------

extern "C" void kernel_launch(void* const* d_in, const int* in_sizes, int n_in,
                              void* d_out, int out_size, void* d_ws, size_t ws_size,
                              hipStream_t stream)
{
    const float* x    = (const float*)d_in[0];
    const float* Wqkv = (const float*)d_in[1];
    const float* bqkv = (const float*)d_in[2];
    const float* Wout = (const float*)d_in[3];
    const float* bout = (const float*)d_in[4];
    float* out = (float*)d_out;

    char* ws = (char*)d_ws;
    short* xbf   = (short*)ws;  ws += (size_t)M_ * C_ * 2;      // 16 MB
    short* wqkvT = (short*)ws;  ws += (size_t)N3_ * C_ * 2;     // 6 MB
    short* woutT = (short*)ws;  ws += (size_t)C_ * C_ * 2;      // 2 MB
    short* qb    = (short*)ws;  ws += (size_t)M_ * C_ * 2;      // 16 MB
    short* kb    = (short*)ws;  ws += (size_t)M_ * C_ * 2;
    short* vtb   = (short*)ws;  ws += (size_t)M_ * C_ * 2;      // V transposed [B,H,DH,T]
    short* yb    = (short*)ws;  ws += (size_t)M_ * C_ * 2;

    // prep
    cast_f32_bf16<<<(M_ * C_ / 8 + 255) / 256, 256, 0, stream>>>(x, xbf, M_ * C_ / 8);
    transpose_cast<<<dim3(N3_ / 64, C_ / 64), 256, 0, stream>>>(Wqkv, wqkvT, C_, N3_);
    transpose_cast<<<dim3(C_ / 64, C_ / 64), 256, 0, stream>>>(Wout, woutT, C_, C_);

    // qkv projection (scatters q, k, and transposed v)
    gemm_bt<1><<<dim3(N3_ / 128, M_ / 128), 256, 0, stream>>>(
        xbf, wqkvT, bqkv, nullptr, qb, kb, vtb);

    // attention
    attn_fwd<<<dim3(T_ / 64, B_ * H_), 256, 0, stream>>>(qb, kb, vtb, yb);

    // output projection
    gemm_bt<0><<<dim3(C_ / 128, M_ / 128), 256, 0, stream>>>(
        yb, woutT, bout, out, nullptr, nullptr, nullptr);
}